// Round 1
// baseline (1118.856 us; speedup 1.0000x reference)
//
#include <hip/hip_runtime.h>
#include <hip/hip_bf16.h>

// BiMamba block, round 1: correct f32 pipeline.
// Dims (compile-time): B=2, L=2048, D_MODEL=512, D_INNER=1024, D_STATE=16,
// D_CONV=4, DT_RANK=32. NTOK = B*L = 4096.

#define DM 512
#define DI 1024
#define DS 16
#define DCV 4
#define DTR 32
#define BB 2
#define LL 2048
#define NTOK (BB * LL)

#define T_CHUNK 128
#define NCHUNK (LL / T_CHUNK)   // 16
#define SUB 32

__device__ __forceinline__ float silu_f(float v) {
    return v / (1.f + __expf(-v));
}

// ---------------------------------------------------------------------------
// Generic tiled f32 GEMM: C[m,n] = sum_k A[m,k]*B[k,n] (+bias[n])
// A rows may be read time-reversed per batch (revA); C rows may be written
// time-reversed (revC). lda/ldc allow strided views (xz buffer, combined).
// ---------------------------------------------------------------------------
template <int BM, int BN, int BK, int TM, int TN>
__launch_bounds__(256)
__global__ void gemm_f32(const float* __restrict__ A,
                         const float* __restrict__ Bw,
                         float* __restrict__ C,
                         const float* __restrict__ bias,
                         int M, int N, int K, int lda, int ldc,
                         int revA, int revC) {
    constexpr int THREADS = (BM / TM) * (BN / TN);  // 256
    __shared__ float As[BK][BM + 4];
    __shared__ float Bs[BK][BN + 4];

    const int m0 = blockIdx.y * BM;
    const int n0 = blockIdx.x * BN;
    const int tid = threadIdx.x;
    const int tm = tid / (BN / TN);
    const int tn = tid % (BN / TN);

    float acc[TM][TN] = {};

    for (int k0 = 0; k0 < K; k0 += BK) {
        // --- load A tile (BM x BK), store transposed into As[k][m]
        constexpr int A_LOADS = (BM * BK) / (THREADS * 4);
#pragma unroll
        for (int l = 0; l < A_LOADS; ++l) {
            int e = (tid + l * THREADS) * 4;
            int row = e / BK, col = e % BK;
            int gm = m0 + row;
            int grow = gm;
            if (revA) { int b = gm / LL; int t = gm % LL; grow = b * LL + (LL - 1 - t); }
            float4 v = *(const float4*)&A[(size_t)grow * lda + k0 + col];
            As[col + 0][row] = v.x;
            As[col + 1][row] = v.y;
            As[col + 2][row] = v.z;
            As[col + 3][row] = v.w;
        }
        // --- load B tile (BK x BN)
        constexpr int B_LOADS = (BK * BN) / (THREADS * 4);
#pragma unroll
        for (int l = 0; l < B_LOADS; ++l) {
            int e = (tid + l * THREADS) * 4;
            int row = e / BN, col = e % BN;
            *(float4*)&Bs[row][col] = *(const float4*)&Bw[(size_t)(k0 + row) * N + n0 + col];
        }
        __syncthreads();

        for (int k = 0; k < BK; ++k) {
            float a[TM], b[TN];
#pragma unroll
            for (int i = 0; i < TM; ++i) a[i] = As[k][tm * TM + i];
#pragma unroll
            for (int j = 0; j < TN; ++j) b[j] = Bs[k][tn * TN + j];
#pragma unroll
            for (int i = 0; i < TM; ++i)
#pragma unroll
                for (int j = 0; j < TN; ++j) acc[i][j] += a[i] * b[j];
        }
        __syncthreads();
    }

#pragma unroll
    for (int i = 0; i < TM; ++i) {
        int gm = m0 + tm * TM + i;
        int grow = gm;
        if (revC) { int b = gm / LL; int t = gm % LL; grow = b * LL + (LL - 1 - t); }
#pragma unroll
        for (int j = 0; j < TN; ++j) {
            int gn = n0 + tn * TN + j;
            float v = acc[i][j];
            if (bias) v += bias[gn];
            C[(size_t)grow * ldc + gn] = v;
        }
    }
}

// ---------------------------------------------------------------------------
// Depthwise causal conv (width 4) + bias + SiLU.  xi lives in xz (ld=2048).
// ---------------------------------------------------------------------------
__launch_bounds__(256)
__global__ void conv_silu(const float* __restrict__ xz,
                          const float* __restrict__ conv_w,
                          const float* __restrict__ conv_b,
                          float* __restrict__ xc) {
    int idx = blockIdx.x * 256 + threadIdx.x;   // over NTOK*DI
    int c = idx % DI;
    int tok = idx / DI;
    int t = tok % LL;
    int b = tok / LL;
    float acc = conv_b[c];
#pragma unroll
    for (int k = 0; k < DCV; ++k) {
        int ts = t + k - (DCV - 1);
        if (ts >= 0)
            acc += conv_w[c * DCV + k] * xz[(size_t)(b * LL + ts) * (2 * DI) + c];
    }
    xc[(size_t)tok * DI + c] = silu_f(acc);
}

// ---------------------------------------------------------------------------
// dt projection + softplus: dtv[tok,c] = softplus(sum_r dbc[tok,r]*dt_w[r,c]+dt_b[c])
// ---------------------------------------------------------------------------
__launch_bounds__(256)
__global__ void dt_proj(const float* __restrict__ dbc,
                        const float* __restrict__ dt_w,
                        const float* __restrict__ dt_b,
                        float* __restrict__ dtv) {
    __shared__ float sdt[DTR];
    int tok = blockIdx.x;
    int tid = threadIdx.x;
    if (tid < DTR) sdt[tid] = dbc[(size_t)tok * 64 + tid];
    __syncthreads();
#pragma unroll
    for (int j = 0; j < DI / 256; ++j) {
        int c = j * 256 + tid;
        float acc = dt_b[c];
#pragma unroll
        for (int r = 0; r < DTR; ++r) acc += sdt[r] * dt_w[r * DI + c];
        float sp = (acc > 20.f) ? acc : log1pf(__expf(acc));
        dtv[(size_t)tok * DI + c] = sp;
    }
}

// ---------------------------------------------------------------------------
// Selective scan, chunked (3 phases). Lane mapping: tid = ci*16 + n,
// block covers 16 channels x 16 states; grid = B * NCHUNK * (DI/16).
// ---------------------------------------------------------------------------
__launch_bounds__(256)
__global__ void scan_phaseA(const float* __restrict__ dtv,
                            const float* __restrict__ xc,
                            const float* __restrict__ dbc,
                            const float* __restrict__ A_log,
                            float* __restrict__ Aprod,
                            float* __restrict__ hend) {
    const int g = blockIdx.x % (DI / 16);
    const int j = (blockIdx.x / (DI / 16)) % NCHUNK;
    const int b = blockIdx.x / ((DI / 16) * NCHUNK);
    const int tid = threadIdx.x;
    const int ci = tid >> 4, n = tid & 15;
    const int c = g * 16 + ci;
    const float Acn = -__expf(A_log[c * DS + n]);

    __shared__ float sdt[SUB][16], sxc[SUB][16], sB[SUB][16];
    float h = 0.f, ap = 1.f;
    const int t0 = j * T_CHUNK;

    for (int s = 0; s < T_CHUNK; s += SUB) {
        __syncthreads();
        for (int e = tid; e < SUB * 16; e += 256) {
            int tt = e >> 4, cc = e & 15;
            size_t rowTok = (size_t)(b * LL + t0 + s + tt);
            sdt[tt][cc] = dtv[rowTok * DI + g * 16 + cc];
            sxc[tt][cc] = xc[rowTok * DI + g * 16 + cc];
            sB[tt][cc]  = dbc[rowTok * 64 + DTR + cc];
        }
        __syncthreads();
#pragma unroll
        for (int tt = 0; tt < SUB; ++tt) {
            float dt = sdt[tt][ci];
            float x  = sxc[tt][ci];
            float Bv = sB[tt][n];
            float dA = __expf(dt * Acn);
            h = dA * h + dt * x * Bv;
            ap *= dA;
        }
    }
    size_t o = ((size_t)(b * NCHUNK + j) * DI + c) * DS + n;
    Aprod[o] = ap;
    hend[o] = h;
}

__launch_bounds__(256)
__global__ void scan_phaseB(const float* __restrict__ Aprod,
                            const float* __restrict__ hend,
                            float* __restrict__ hinit) {
    int idx = blockIdx.x * 256 + threadIdx.x;   // over B*DI*16
    int b = idx / (DI * DS);
    int p = idx % (DI * DS);
    float h = 0.f;
#pragma unroll
    for (int j = 0; j < NCHUNK; ++j) {
        size_t o = ((size_t)(b * NCHUNK + j) * DI) * DS + p;
        hinit[o] = h;
        h = Aprod[o] * h + hend[o];
    }
}

__launch_bounds__(256)
__global__ void scan_phaseC(const float* __restrict__ dtv,
                            const float* __restrict__ xc,
                            const float* __restrict__ dbc,
                            const float* __restrict__ xz,   // z half
                            const float* __restrict__ A_log,
                            const float* __restrict__ Dskip,
                            const float* __restrict__ hinit,
                            float* __restrict__ ybuf) {
    const int g = blockIdx.x % (DI / 16);
    const int j = (blockIdx.x / (DI / 16)) % NCHUNK;
    const int b = blockIdx.x / ((DI / 16) * NCHUNK);
    const int tid = threadIdx.x;
    const int ci = tid >> 4, n = tid & 15;
    const int c = g * 16 + ci;
    const float Acn = -__expf(A_log[c * DS + n]);
    const float Dsk = Dskip[c];

    __shared__ float sdt[SUB][16], sxc[SUB][16], sB[SUB][16], sC[SUB][16], sz[SUB][16];
    float h = hinit[((size_t)(b * NCHUNK + j) * DI + c) * DS + n];
    const int t0 = j * T_CHUNK;

    for (int s = 0; s < T_CHUNK; s += SUB) {
        __syncthreads();
        for (int e = tid; e < SUB * 16; e += 256) {
            int tt = e >> 4, cc = e & 15;
            size_t rowTok = (size_t)(b * LL + t0 + s + tt);
            sdt[tt][cc] = dtv[rowTok * DI + g * 16 + cc];
            sxc[tt][cc] = xc[rowTok * DI + g * 16 + cc];
            sB[tt][cc]  = dbc[rowTok * 64 + DTR + cc];
            sC[tt][cc]  = dbc[rowTok * 64 + DTR + DS + cc];
            sz[tt][cc]  = xz[rowTok * (2 * DI) + DI + g * 16 + cc];
        }
        __syncthreads();
#pragma unroll
        for (int tt = 0; tt < SUB; ++tt) {
            float dt = sdt[tt][ci];
            float x  = sxc[tt][ci];
            float Bv = sB[tt][n];
            float dA = __expf(dt * Acn);
            h = dA * h + dt * x * Bv;
            float contrib = h * sC[tt][n];
            contrib += __shfl_xor(contrib, 1);
            contrib += __shfl_xor(contrib, 2);
            contrib += __shfl_xor(contrib, 4);
            contrib += __shfl_xor(contrib, 8);
            if (n == 0) {
                float y = contrib + x * Dsk;
                float zv = sz[tt][ci];
                y *= silu_f(zv);
                ybuf[(size_t)(b * LL + t0 + s + tt) * DI + c] = y;
            }
        }
    }
}

// ---------------------------------------------------------------------------
extern "C" void kernel_launch(void* const* d_in, const int* in_sizes, int n_in,
                              void* d_out, int out_size, void* d_ws, size_t ws_size,
                              hipStream_t stream) {
    const float* x = (const float*)d_in[0];
    const float* fuse_w = (const float*)d_in[19];
    const float* fuse_b = (const float*)d_in[20];
    float* out = (float*)d_out;

    // workspace carve-up (f32 elements)
    float* ws = (float*)d_ws;
    float* xz       = ws;                                    // NTOK*2048
    float* xc       = xz + (size_t)NTOK * 2 * DI;            // NTOK*1024
    float* dtv      = xc + (size_t)NTOK * DI;                // NTOK*1024
    float* dbc      = dtv + (size_t)NTOK * DI;               // NTOK*64
    float* ybuf     = dbc + (size_t)NTOK * 64;               // NTOK*1024
    float* combined = ybuf + (size_t)NTOK * DI;              // NTOK*1024
    float* Aprod    = combined + (size_t)NTOK * DI;          // B*NCHUNK*DI*16
    float* hend     = Aprod + (size_t)BB * NCHUNK * DI * DS;
    float* hinit    = hend + (size_t)BB * NCHUNK * DI * DS;

    for (int dir = 0; dir < 2; ++dir) {
        const float* in_w    = (const float*)d_in[1 + dir * 9 + 0];
        const float* conv_w  = (const float*)d_in[1 + dir * 9 + 1];
        const float* conv_b  = (const float*)d_in[1 + dir * 9 + 2];
        const float* xproj_w = (const float*)d_in[1 + dir * 9 + 3];
        const float* dt_w    = (const float*)d_in[1 + dir * 9 + 4];
        const float* dt_b    = (const float*)d_in[1 + dir * 9 + 5];
        const float* A_log   = (const float*)d_in[1 + dir * 9 + 6];
        const float* D_skip  = (const float*)d_in[1 + dir * 9 + 7];
        const float* out_w   = (const float*)d_in[1 + dir * 9 + 8];
        const int rev = (dir == 1);

        // 1. in_proj: xz = x(perm) @ in_w   (4096 x 2048 x 512)
        gemm_f32<128, 128, 16, 8, 8><<<dim3(2 * DI / 128, NTOK / 128), 256, 0, stream>>>(
            x, in_w, xz, nullptr, NTOK, 2 * DI, DM, DM, 2 * DI, rev, 0);

        // 2. conv + silu
        conv_silu<<<NTOK * DI / 256, 256, 0, stream>>>(xz, conv_w, conv_b, xc);

        // 3. xproj: dbc = xc @ xproj_w   (4096 x 64 x 1024)
        gemm_f32<64, 64, 16, 4, 4><<<dim3(1, NTOK / 64), 256, 0, stream>>>(
            xc, xproj_w, dbc, nullptr, NTOK, 64, DI, DI, 64, 0, 0);

        // 4. dt projection + softplus
        dt_proj<<<NTOK, 256, 0, stream>>>(dbc, dt_w, dt_b, dtv);

        // 5-7. chunked selective scan
        scan_phaseA<<<BB * NCHUNK * (DI / 16), 256, 0, stream>>>(
            dtv, xc, dbc, A_log, Aprod, hend);
        scan_phaseB<<<BB * DI * DS / 256, 256, 0, stream>>>(Aprod, hend, hinit);
        scan_phaseC<<<BB * NCHUNK * (DI / 16), 256, 0, stream>>>(
            dtv, xc, dbc, xz, A_log, D_skip, hinit, ybuf);

        // 8. out_proj into combined (bwd: time-reversed rows, right half)
        gemm_f32<128, 128, 16, 8, 8><<<dim3(DM / 128, NTOK / 128), 256, 0, stream>>>(
            ybuf, out_w, combined + dir * DM, nullptr, NTOK, DM, DI, DI, 2 * DM, 0, rev);
    }

    // 9. fuse: out = combined @ fuse_w + fuse_b
    gemm_f32<128, 128, 16, 8, 8><<<dim3(DM / 128, NTOK / 128), 256, 0, stream>>>(
        combined, fuse_w, out, fuse_b, NTOK, DM, 2 * DM, 2 * DM, DM, 0, 0);
}

// Round 2
// 598.696 us; speedup vs baseline: 1.8688x; 1.8688x over previous
//
#include <hip/hip_runtime.h>
#include <hip/hip_bf16.h>

// BiMamba block, round 2: split-bf16 MFMA for the large GEMMs.
// in_proj / out_proj / fuse -> mfma_f32_16x16x32_bf16 with hi/lo operand
// splitting (3 MFMAs per fragment pair, ~fp32 accuracy).
// xproj -> f32 with 4-way split-K atomics. conv/dt/scan unchanged.

#define DM 512
#define DI 1024
#define DS 16
#define DCV 4
#define DTR 32
#define BB 2
#define LL 2048
#define NTOK (BB * LL)

#define T_CHUNK 128
#define NCHUNK (LL / T_CHUNK)   // 16
#define SUB 32

typedef unsigned short ushortT;
typedef unsigned int u32;
typedef __attribute__((ext_vector_type(8))) short short8;
typedef __attribute__((ext_vector_type(4))) float floatx4;

__device__ __forceinline__ float silu_f(float v) {
    return v / (1.f + __expf(-v));
}

__device__ __forceinline__ ushortT f2bf(float f) {
    union { float f; u32 u; } v; v.f = f;
    u32 u = v.u;
    u32 r = (u + 0x7fffu + ((u >> 16) & 1u)) >> 16;   // RNE
    return (ushortT)r;
}
__device__ __forceinline__ float bf2f(ushortT h) {
    union { float f; u32 u; } v; v.u = ((u32)h) << 16; return v.f;
}

__device__ __forceinline__ void load_lds16(const ushortT* g, ushortT* l) {
    __builtin_amdgcn_global_load_lds((const __attribute__((address_space(1))) u32*)g,
                                     (__attribute__((address_space(3))) u32*)l, 16, 0, 0);
}

// ---------------------------------------------------------------------------
// split/transpose preprocessing
// ---------------------------------------------------------------------------
__launch_bounds__(256)
__global__ void split_f32(const float* __restrict__ X, ushortT* __restrict__ H,
                          ushortT* __restrict__ L) {
    int i = (blockIdx.x * 256 + threadIdx.x) * 4;
    float4 v = *(const float4*)&X[i];
    ushortT h0 = f2bf(v.x), h1 = f2bf(v.y), h2 = f2bf(v.z), h3 = f2bf(v.w);
    H[i + 0] = h0; H[i + 1] = h1; H[i + 2] = h2; H[i + 3] = h3;
    L[i + 0] = f2bf(v.x - bf2f(h0));
    L[i + 1] = f2bf(v.y - bf2f(h1));
    L[i + 2] = f2bf(v.z - bf2f(h2));
    L[i + 3] = f2bf(v.w - bf2f(h3));
}

// W: K x N f32 row-major  ->  Wt_hi/Wt_lo: N x K bf16 row-major
__launch_bounds__(256)
__global__ void transpose_split(const float* __restrict__ W, ushortT* __restrict__ Wh,
                                ushortT* __restrict__ Wl, int K, int N) {
    __shared__ float t[32][33];
    int kb = blockIdx.y * 32, nb = blockIdx.x * 32;
    int tid = threadIdx.x;
    int r = tid / 8, c = (tid % 8) * 4;
    float4 v = *(const float4*)&W[(size_t)(kb + r) * N + nb + c];
    t[r][c + 0] = v.x; t[r][c + 1] = v.y; t[r][c + 2] = v.z; t[r][c + 3] = v.w;
    __syncthreads();
#pragma unroll
    for (int i = 0; i < 4; ++i) {
        float x = t[c + i][r];
        ushortT h = f2bf(x);
        size_t o = (size_t)(nb + r) * K + kb + c + i;
        Wh[o] = h;
        Wl[o] = f2bf(x - bf2f(h));
    }
}

__launch_bounds__(256)
__global__ void zero_f32(float* __restrict__ p) {
    int i = (blockIdx.x * 256 + threadIdx.x) * 4;
    float4 z = {0.f, 0.f, 0.f, 0.f};
    *(float4*)&p[i] = z;
}

// ---------------------------------------------------------------------------
// split-bf16 MFMA GEMM.  C = A @ B.
// A given as hi/lo planes, M x K row-major. B given transposed (N x K) hi/lo.
// OUTMODE 0: f32 C; 1: f32 C + bias; 2: bf16 hi/lo plane outputs.
// ---------------------------------------------------------------------------
template <int BM, int BN, int WM, int WN, int OUTMODE>
__launch_bounds__(256)
__global__ void gemm_bf16s(const ushortT* __restrict__ Ahi, const ushortT* __restrict__ Alo,
                           const ushortT* __restrict__ Bhi, const ushortT* __restrict__ Blo,
                           float* __restrict__ C, const float* __restrict__ bias,
                           ushortT* __restrict__ Chi, ushortT* __restrict__ Clo,
                           int M, int N, int K, int ldc, int revA, int revC) {
    constexpr int BK = 32;
    constexpr int MI = WM / 16, NI = WN / 16;
    __shared__ ushortT sAh[BM * BK], sAl[BM * BK], sBh[BN * BK], sBl[BN * BK];

    const int tid = threadIdx.x;
    const int wave = tid >> 6, lane = tid & 63;
    const int wm = wave >> 1, wn = wave & 1;          // 2x2 wave grid
    const int m0 = blockIdx.y * BM, n0 = blockIdx.x * BN;
    const int quad = lane >> 4, l16 = lane & 15;
    const int srow = lane >> 2;                        // staging: row within 16
    const int scol = (lane & 3) * 8;                   // staging: ushort col

    floatx4 acc[MI][NI] = {};

    for (int k0 = 0; k0 < K; k0 += BK) {
        __syncthreads();
        // stage A planes: 16 rows (64 B each) per instruction
#pragma unroll
        for (int s = wave; s < BM / 16; s += 4) {
            int gm = m0 + s * 16 + srow;
            int grow = gm;
            if (revA) { int b = gm >> 11; int t = gm & 2047; grow = (b << 11) + (2047 - t); }
            size_t goff = (size_t)grow * K + k0 + scol;
            load_lds16(Ahi + goff, sAh + s * 16 * BK);
            load_lds16(Alo + goff, sAl + s * 16 * BK);
        }
#pragma unroll
        for (int s = wave; s < BN / 16; s += 4) {
            int gn = n0 + s * 16 + srow;
            size_t goff = (size_t)gn * K + k0 + scol;
            load_lds16(Bhi + goff, sBh + s * 16 * BK);
            load_lds16(Blo + goff, sBl + s * 16 * BK);
        }
        __syncthreads();

        short8 ah[MI], al[MI], bh[NI], bl[NI];
#pragma unroll
        for (int i = 0; i < MI; ++i) {
            int r = wm * WM + i * 16 + l16;
            ah[i] = *(const short8*)(sAh + r * BK + quad * 8);
            al[i] = *(const short8*)(sAl + r * BK + quad * 8);
        }
#pragma unroll
        for (int j = 0; j < NI; ++j) {
            int r = wn * WN + j * 16 + l16;
            bh[j] = *(const short8*)(sBh + r * BK + quad * 8);
            bl[j] = *(const short8*)(sBl + r * BK + quad * 8);
        }
#pragma unroll
        for (int i = 0; i < MI; ++i)
#pragma unroll
            for (int j = 0; j < NI; ++j) {
                acc[i][j] = __builtin_amdgcn_mfma_f32_16x16x32_bf16(ah[i], bh[j], acc[i][j], 0, 0, 0);
                acc[i][j] = __builtin_amdgcn_mfma_f32_16x16x32_bf16(al[i], bh[j], acc[i][j], 0, 0, 0);
                acc[i][j] = __builtin_amdgcn_mfma_f32_16x16x32_bf16(ah[i], bl[j], acc[i][j], 0, 0, 0);
            }
    }

    // epilogue: C/D layout col=lane&15, row=quad*4+reg
#pragma unroll
    for (int i = 0; i < MI; ++i) {
#pragma unroll
        for (int r = 0; r < 4; ++r) {
            int gm = m0 + wm * WM + i * 16 + quad * 4 + r;
            int grow = gm;
            if (revC) { int b = gm >> 11; int t = gm & 2047; grow = (b << 11) + (2047 - t); }
#pragma unroll
            for (int j = 0; j < NI; ++j) {
                int gn = n0 + wn * WN + j * 16 + l16;
                float v = acc[i][j][r];
                if (OUTMODE == 1) v += bias[gn];
                if (OUTMODE <= 1) {
                    C[(size_t)grow * ldc + gn] = v;
                } else {
                    ushortT h = f2bf(v);
                    size_t o = (size_t)grow * ldc + gn;
                    Chi[o] = h;
                    Clo[o] = f2bf(v - bf2f(h));
                }
            }
        }
    }
}

// ---------------------------------------------------------------------------
// f32 GEMM (kept for xproj), now with split-K via gridDim.z + atomicAdd.
// ---------------------------------------------------------------------------
template <int BM, int BN, int BK, int TM, int TN>
__launch_bounds__(256)
__global__ void gemm_f32(const float* __restrict__ A,
                         const float* __restrict__ Bw,
                         float* __restrict__ C,
                         int M, int N, int K, int lda, int ldc, int splitk) {
    constexpr int THREADS = (BM / TM) * (BN / TN);
    __shared__ float As[BK][BM + 4];
    __shared__ float Bs[BK][BN + 4];

    const int m0 = blockIdx.y * BM;
    const int n0 = blockIdx.x * BN;
    const int tid = threadIdx.x;
    const int tm = tid / (BN / TN);
    const int tn = tid % (BN / TN);

    int klen = K / gridDim.z;
    int kb = blockIdx.z * klen;

    float acc[TM][TN] = {};

    for (int k0 = kb; k0 < kb + klen; k0 += BK) {
        constexpr int A_LOADS = (BM * BK) / (THREADS * 4);
#pragma unroll
        for (int l = 0; l < A_LOADS; ++l) {
            int e = (tid + l * THREADS) * 4;
            int row = e / BK, col = e % BK;
            float4 v = *(const float4*)&A[(size_t)(m0 + row) * lda + k0 + col];
            As[col + 0][row] = v.x;
            As[col + 1][row] = v.y;
            As[col + 2][row] = v.z;
            As[col + 3][row] = v.w;
        }
        constexpr int B_LOADS = (BK * BN) / (THREADS * 4);
#pragma unroll
        for (int l = 0; l < B_LOADS; ++l) {
            int e = (tid + l * THREADS) * 4;
            int row = e / BN, col = e % BN;
            *(float4*)&Bs[row][col] = *(const float4*)&Bw[(size_t)(k0 + row) * N + n0 + col];
        }
        __syncthreads();

        for (int k = 0; k < BK; ++k) {
            float a[TM], b[TN];
#pragma unroll
            for (int i = 0; i < TM; ++i) a[i] = As[k][tm * TM + i];
#pragma unroll
            for (int j = 0; j < TN; ++j) b[j] = Bs[k][tn * TN + j];
#pragma unroll
            for (int i = 0; i < TM; ++i)
#pragma unroll
                for (int j = 0; j < TN; ++j) acc[i][j] += a[i] * b[j];
        }
        __syncthreads();
    }

#pragma unroll
    for (int i = 0; i < TM; ++i) {
        int gm = m0 + tm * TM + i;
#pragma unroll
        for (int j = 0; j < TN; ++j) {
            int gn = n0 + tn * TN + j;
            if (splitk) atomicAdd(&C[(size_t)gm * ldc + gn], acc[i][j]);
            else C[(size_t)gm * ldc + gn] = acc[i][j];
        }
    }
}

// ---------------------------------------------------------------------------
// depthwise causal conv(4) + bias + SiLU
// ---------------------------------------------------------------------------
__launch_bounds__(256)
__global__ void conv_silu(const float* __restrict__ xz,
                          const float* __restrict__ conv_w,
                          const float* __restrict__ conv_b,
                          float* __restrict__ xc) {
    int idx = blockIdx.x * 256 + threadIdx.x;
    int c = idx % DI;
    int tok = idx / DI;
    int t = tok % LL;
    int b = tok / LL;
    float acc = conv_b[c];
#pragma unroll
    for (int k = 0; k < DCV; ++k) {
        int ts = t + k - (DCV - 1);
        if (ts >= 0)
            acc += conv_w[c * DCV + k] * xz[(size_t)(b * LL + ts) * (2 * DI) + c];
    }
    xc[(size_t)tok * DI + c] = silu_f(acc);
}

// ---------------------------------------------------------------------------
// dt projection + softplus
// ---------------------------------------------------------------------------
__launch_bounds__(256)
__global__ void dt_proj(const float* __restrict__ dbc,
                        const float* __restrict__ dt_w,
                        const float* __restrict__ dt_b,
                        float* __restrict__ dtv) {
    __shared__ float sdt[DTR];
    int tok = blockIdx.x;
    int tid = threadIdx.x;
    if (tid < DTR) sdt[tid] = dbc[(size_t)tok * 64 + tid];
    __syncthreads();
#pragma unroll
    for (int j = 0; j < DI / 256; ++j) {
        int c = j * 256 + tid;
        float acc = dt_b[c];
#pragma unroll
        for (int r = 0; r < DTR; ++r) acc += sdt[r] * dt_w[r * DI + c];
        float sp = (acc > 20.f) ? acc : log1pf(__expf(acc));
        dtv[(size_t)tok * DI + c] = sp;
    }
}

// ---------------------------------------------------------------------------
// selective scan, chunked (3 phases)
// ---------------------------------------------------------------------------
__launch_bounds__(256)
__global__ void scan_phaseA(const float* __restrict__ dtv,
                            const float* __restrict__ xc,
                            const float* __restrict__ dbc,
                            const float* __restrict__ A_log,
                            float* __restrict__ Aprod,
                            float* __restrict__ hend) {
    const int g = blockIdx.x % (DI / 16);
    const int j = (blockIdx.x / (DI / 16)) % NCHUNK;
    const int b = blockIdx.x / ((DI / 16) * NCHUNK);
    const int tid = threadIdx.x;
    const int ci = tid >> 4, n = tid & 15;
    const int c = g * 16 + ci;
    const float Acn = -__expf(A_log[c * DS + n]);

    __shared__ float sdt[SUB][16], sxc[SUB][16], sB[SUB][16];
    float h = 0.f, ap = 1.f;
    const int t0 = j * T_CHUNK;

    for (int s = 0; s < T_CHUNK; s += SUB) {
        __syncthreads();
        for (int e = tid; e < SUB * 16; e += 256) {
            int tt = e >> 4, cc = e & 15;
            size_t rowTok = (size_t)(b * LL + t0 + s + tt);
            sdt[tt][cc] = dtv[rowTok * DI + g * 16 + cc];
            sxc[tt][cc] = xc[rowTok * DI + g * 16 + cc];
            sB[tt][cc]  = dbc[rowTok * 64 + DTR + cc];
        }
        __syncthreads();
#pragma unroll
        for (int tt = 0; tt < SUB; ++tt) {
            float dt = sdt[tt][ci];
            float x  = sxc[tt][ci];
            float Bv = sB[tt][n];
            float dA = __expf(dt * Acn);
            h = dA * h + dt * x * Bv;
            ap *= dA;
        }
    }
    size_t o = ((size_t)(b * NCHUNK + j) * DI + c) * DS + n;
    Aprod[o] = ap;
    hend[o] = h;
}

__launch_bounds__(256)
__global__ void scan_phaseB(const float* __restrict__ Aprod,
                            const float* __restrict__ hend,
                            float* __restrict__ hinit) {
    int idx = blockIdx.x * 256 + threadIdx.x;
    int b = idx / (DI * DS);
    int p = idx % (DI * DS);
    float h = 0.f;
#pragma unroll
    for (int j = 0; j < NCHUNK; ++j) {
        size_t o = ((size_t)(b * NCHUNK + j) * DI) * DS + p;
        hinit[o] = h;
        h = Aprod[o] * h + hend[o];
    }
}

__launch_bounds__(256)
__global__ void scan_phaseC(const float* __restrict__ dtv,
                            const float* __restrict__ xc,
                            const float* __restrict__ dbc,
                            const float* __restrict__ xz,   // z half
                            const float* __restrict__ A_log,
                            const float* __restrict__ Dskip,
                            const float* __restrict__ hinit,
                            ushortT* __restrict__ yh,
                            ushortT* __restrict__ yl) {
    const int g = blockIdx.x % (DI / 16);
    const int j = (blockIdx.x / (DI / 16)) % NCHUNK;
    const int b = blockIdx.x / ((DI / 16) * NCHUNK);
    const int tid = threadIdx.x;
    const int ci = tid >> 4, n = tid & 15;
    const int c = g * 16 + ci;
    const float Acn = -__expf(A_log[c * DS + n]);
    const float Dsk = Dskip[c];

    __shared__ float sdt[SUB][16], sxc[SUB][16], sB[SUB][16], sC[SUB][16], sz[SUB][16];
    float h = hinit[((size_t)(b * NCHUNK + j) * DI + c) * DS + n];
    const int t0 = j * T_CHUNK;

    for (int s = 0; s < T_CHUNK; s += SUB) {
        __syncthreads();
        for (int e = tid; e < SUB * 16; e += 256) {
            int tt = e >> 4, cc = e & 15;
            size_t rowTok = (size_t)(b * LL + t0 + s + tt);
            sdt[tt][cc] = dtv[rowTok * DI + g * 16 + cc];
            sxc[tt][cc] = xc[rowTok * DI + g * 16 + cc];
            sB[tt][cc]  = dbc[rowTok * 64 + DTR + cc];
            sC[tt][cc]  = dbc[rowTok * 64 + DTR + DS + cc];
            sz[tt][cc]  = xz[rowTok * (2 * DI) + DI + g * 16 + cc];
        }
        __syncthreads();
#pragma unroll
        for (int tt = 0; tt < SUB; ++tt) {
            float dt = sdt[tt][ci];
            float x  = sxc[tt][ci];
            float Bv = sB[tt][n];
            float dA = __expf(dt * Acn);
            h = dA * h + dt * x * Bv;
            float contrib = h * sC[tt][n];
            contrib += __shfl_xor(contrib, 1);
            contrib += __shfl_xor(contrib, 2);
            contrib += __shfl_xor(contrib, 4);
            contrib += __shfl_xor(contrib, 8);
            if (n == 0) {
                float y = contrib + x * Dsk;
                float zv = sz[tt][ci];
                y *= silu_f(zv);
                size_t o = (size_t)(b * LL + t0 + s + tt) * DI + c;
                ushortT hh = f2bf(y);
                yh[o] = hh;
                yl[o] = f2bf(y - bf2f(hh));
            }
        }
    }
}

// ---------------------------------------------------------------------------
extern "C" void kernel_launch(void* const* d_in, const int* in_sizes, int n_in,
                              void* d_out, int out_size, void* d_ws, size_t ws_size,
                              hipStream_t stream) {
    const float* x = (const float*)d_in[0];
    const float* fuse_w = (const float*)d_in[19];
    const float* fuse_b = (const float*)d_in[20];
    float* out = (float*)d_out;

    char* p = (char*)d_ws;
    auto alloc = [&](size_t bytes) { char* r = p; p += (bytes + 255) & ~(size_t)255; return r; };

    float* xz   = (float*)alloc((size_t)NTOK * 2 * DI * 4);
    float* xc   = (float*)alloc((size_t)NTOK * DI * 4);
    float* dtv  = (float*)alloc((size_t)NTOK * DI * 4);
    float* dbc  = (float*)alloc((size_t)NTOK * 64 * 4);
    float* Aprod = (float*)alloc((size_t)BB * NCHUNK * DI * DS * 4);
    float* hend  = (float*)alloc((size_t)BB * NCHUNK * DI * DS * 4);
    float* hinit = (float*)alloc((size_t)BB * NCHUNK * DI * DS * 4);
    ushortT* xh   = (ushortT*)alloc((size_t)NTOK * DM * 2);
    ushortT* xl   = (ushortT*)alloc((size_t)NTOK * DM * 2);
    ushortT* wtih = (ushortT*)alloc((size_t)2 * DI * DM * 2);   // in_w^T planes
    ushortT* wtil = (ushortT*)alloc((size_t)2 * DI * DM * 2);
    ushortT* wtoh = (ushortT*)alloc((size_t)DM * DI * 2);       // out_w^T planes
    ushortT* wtol = (ushortT*)alloc((size_t)DM * DI * 2);
    ushortT* wtfh = (ushortT*)alloc((size_t)DM * 2 * DM * 2);   // fuse_w^T planes
    ushortT* wtfl = (ushortT*)alloc((size_t)DM * 2 * DM * 2);
    ushortT* yh   = (ushortT*)alloc((size_t)NTOK * DI * 2);
    ushortT* yl   = (ushortT*)alloc((size_t)NTOK * DI * 2);
    ushortT* ch   = (ushortT*)alloc((size_t)NTOK * 2 * DM * 2); // combined planes
    ushortT* cl   = (ushortT*)alloc((size_t)NTOK * 2 * DM * 2);

    // one-time preprocessing
    split_f32<<<NTOK * DM / 1024, 256, 0, stream>>>(x, xh, xl);
    transpose_split<<<dim3(DM / 32, (2 * DM) / 32), 256, 0, stream>>>(fuse_w, wtfh, wtfl, 2 * DM, DM);

    for (int dir = 0; dir < 2; ++dir) {
        const float* in_w    = (const float*)d_in[1 + dir * 9 + 0];
        const float* conv_w  = (const float*)d_in[1 + dir * 9 + 1];
        const float* conv_b  = (const float*)d_in[1 + dir * 9 + 2];
        const float* xproj_w = (const float*)d_in[1 + dir * 9 + 3];
        const float* dt_w    = (const float*)d_in[1 + dir * 9 + 4];
        const float* dt_b    = (const float*)d_in[1 + dir * 9 + 5];
        const float* A_log   = (const float*)d_in[1 + dir * 9 + 6];
        const float* D_skip  = (const float*)d_in[1 + dir * 9 + 7];
        const float* out_w   = (const float*)d_in[1 + dir * 9 + 8];
        const int rev = (dir == 1);

        // in_proj: xz = x(rev?) @ in_w   (4096 x 2048 x 512), MFMA
        transpose_split<<<dim3((2 * DI) / 32, DM / 32), 256, 0, stream>>>(in_w, wtih, wtil, DM, 2 * DI);
        gemm_bf16s<128, 128, 64, 64, 0><<<dim3(2 * DI / 128, NTOK / 128), 256, 0, stream>>>(
            xh, xl, wtih, wtil, xz, nullptr, nullptr, nullptr,
            NTOK, 2 * DI, DM, 2 * DI, rev, 0);

        conv_silu<<<NTOK * DI / 256, 256, 0, stream>>>(xz, conv_w, conv_b, xc);

        // xproj: dbc = xc @ xproj_w  (4096 x 64 x 1024), f32 split-K=4
        zero_f32<<<NTOK * 64 / 1024, 256, 0, stream>>>(dbc);
        gemm_f32<64, 64, 16, 4, 4><<<dim3(1, NTOK / 64, 4), 256, 0, stream>>>(
            xc, xproj_w, dbc, NTOK, 64, DI, DI, 64, 1);

        dt_proj<<<NTOK, 256, 0, stream>>>(dbc, dt_w, dt_b, dtv);

        scan_phaseA<<<BB * NCHUNK * (DI / 16), 256, 0, stream>>>(
            dtv, xc, dbc, A_log, Aprod, hend);
        scan_phaseB<<<BB * DI * DS / 256, 256, 0, stream>>>(Aprod, hend, hinit);
        scan_phaseC<<<BB * NCHUNK * (DI / 16), 256, 0, stream>>>(
            dtv, xc, dbc, xz, A_log, D_skip, hinit, yh, yl);

        // out_proj: combined[:, dir*DM:] = y(revC?) @ out_w  (4096 x 512 x 1024), MFMA -> bf16 planes
        transpose_split<<<dim3(DM / 32, DI / 32), 256, 0, stream>>>(out_w, wtoh, wtol, DI, DM);
        gemm_bf16s<64, 64, 32, 32, 2><<<dim3(DM / 64, NTOK / 64), 256, 0, stream>>>(
            yh, yl, wtoh, wtol, nullptr, nullptr, ch + dir * DM, cl + dir * DM,
            NTOK, DM, DI, 2 * DM, 0, rev);
    }

    // fuse: out = combined @ fuse_w + fuse_b  (4096 x 512 x 1024), MFMA
    gemm_bf16s<64, 64, 32, 32, 1><<<dim3(DM / 64, NTOK / 64), 256, 0, stream>>>(
        ch, cl, wtfh, wtfl, out, fuse_b, nullptr, nullptr,
        NTOK, DM, 2 * DM, DM, 0, 0);
}